// Round 2
// baseline (301.669 us; speedup 1.0000x reference)
//
#include <hip/hip_runtime.h>
#include <hip/hip_bf16.h>

#define N_NODES 50000
#define N_EDGES 800000
#define D 64

// ---------- helpers ----------
__device__ __forceinline__ float b2f(unsigned short h) {
    return __uint_as_float(((unsigned)h) << 16);
}
__device__ __forceinline__ unsigned short f2b(float f) {
    __hip_bfloat16 t = __float2bfloat16(f);
    return *reinterpret_cast<unsigned short*>(&t);
}
// monotonic float<->uint encoding so unsigned atomicMin == float min
__device__ __forceinline__ unsigned f2ord(float f) {
    unsigned u = __float_as_uint(f);
    return (u & 0x80000000u) ? ~u : (u | 0x80000000u);
}
__device__ __forceinline__ float ord2f(unsigned o) {
    return __uint_as_float((o & 0x80000000u) ? (o ^ 0x80000000u) : ~o);
}

// ---------- kernel 0: runtime dtype / index-width detection ----------
// flags[0] = 1 if float tensors are fp32 (else bf16)
// flags[1] = 1 if src/dst are int64 (else int32)
__global__ void detect_mode(const void* feat, const void* srcv, unsigned* flags) {
    const int t = threadIdx.x;          // 128 threads = 2 waves
    if (t < 64) {
        // probe even bf16 elements: in an fp32 buffer these are the garbage
        // low-mantissa halves (log-uniform magnitudes); in bf16 they are N(0,1).
        const unsigned short* p = (const unsigned short*)feat;
        float x = b2f(p[2 * t]);
        float a = fabsf(x);
        bool insane = !(a <= 64.f) || (x != 0.f && a < 9.3132e-10f); // NaN/huge/subnormal-ish
        unsigned long long m = __ballot(insane);
        if (t == 0) flags[0] = (__popcll(m) >= 8) ? 1u : 0u;
    } else {
        // odd int32 words: all zero <=> little-endian int64 high words
        const int* s32 = (const int*)srcv;
        int v = s32[2 * (t - 64) + 1];
        unsigned long long m = __ballot(v == 0);
        if (t == 64) flags[1] = (__popcll(m) >= 32) ? 1u : 0u;
    }
}

// ---------- kernel 1: T = feat @ W_theta -> d_out ; seed M = ord(T) ----------
__global__ __launch_bounds__(256, 2)
void node_theta(const void* __restrict__ featv, const void* __restrict__ Wtv,
                unsigned* __restrict__ flags, void* __restrict__ outv) {
    const unsigned fp32mode = flags[0];
    unsigned* M = flags + 64;                 // M starts at ws+256
    const int lane = threadIdx.x & 63;
    const int wid  = threadIdx.x >> 6;

    float wt[D];
    if (fp32mode) {
        const float* W = (const float*)Wtv;
#pragma unroll
        for (int k = 0; k < D; ++k) wt[k] = W[k * D + lane];
    } else {
        const unsigned short* W = (const unsigned short*)Wtv;
#pragma unroll
        for (int k = 0; k < D; ++k) wt[k] = b2f(W[k * D + lane]);
    }

    const int nW = gridDim.x << 2;
    for (int r = (blockIdx.x << 2) + wid; r < N_NODES; r += nW) {
        float x = fp32mode ? ((const float*)featv)[r * D + lane]
                           : b2f(((const unsigned short*)featv)[r * D + lane]);
        float at = 0.f;
#pragma unroll
        for (int k = 0; k < D; ++k)
            at = fmaf(__shfl(x, k, 64), wt[k], at);
        if (fp32mode) {
            ((float*)outv)[r * D + lane] = at;
            M[r * D + lane] = f2ord(at);                 // self-loop seed
        } else {
            unsigned short tb = f2b(at);
            ((unsigned short*)outv)[r * D + lane] = tb;
            M[r * D + lane] = f2ord(b2f(tb));            // match edge-read rounding
        }
    }
}

// ---------- kernel 2: scatter-min of T[src] into M[dst] ----------
__global__ __launch_bounds__(256)
void edge_scatter(const void* __restrict__ srcv, const void* __restrict__ dstv,
                  const void* __restrict__ outv, unsigned* __restrict__ flags) {
    const unsigned fp32mode = flags[0];
    const unsigned idx64    = flags[1];
    unsigned* M = flags + 64;
    const int lane = threadIdx.x & 63;
    const int wid  = threadIdx.x >> 6;
    const int e = (blockIdx.x << 2) + wid;    // grid sized exactly
    int s, d;
    if (idx64) {
        s = (int)((const long long*)srcv)[e];
        d = (int)((const long long*)dstv)[e];
    } else {
        s = ((const int*)srcv)[e];
        d = ((const int*)dstv)[e];
    }
    s = min(max(s, 0), N_NODES - 1);          // structural OOB guard
    d = min(max(d, 0), N_NODES - 1);
    if (s == d) return;                       // self-loops seeded in k1
    float v = fp32mode ? ((const float*)outv)[s * D + lane]
                       : b2f(((const unsigned short*)outv)[s * D + lane]);
    atomicMin(&M[d * D + lane], f2ord(v));
}

// ---------- kernel 3: out = feat@Wt + feat@Wp + bt + bp - ord2f(M) ----------
__global__ __launch_bounds__(256, 2)
void finalize(const void* __restrict__ featv,
              const void* __restrict__ Wtv, const void* __restrict__ btv,
              const void* __restrict__ Wpv, const void* __restrict__ bpv,
              unsigned* __restrict__ flags, void* __restrict__ outv) {
    const unsigned fp32mode = flags[0];
    const unsigned* M = flags + 64;
    const int lane = threadIdx.x & 63;
    const int wid  = threadIdx.x >> 6;

    float wt[D], wp[D], bsum;
    if (fp32mode) {
        const float* Wt = (const float*)Wtv;
        const float* Wp = (const float*)Wpv;
#pragma unroll
        for (int k = 0; k < D; ++k) { wt[k] = Wt[k * D + lane]; wp[k] = Wp[k * D + lane]; }
        bsum = ((const float*)btv)[lane] + ((const float*)bpv)[lane];
    } else {
        const unsigned short* Wt = (const unsigned short*)Wtv;
        const unsigned short* Wp = (const unsigned short*)Wpv;
#pragma unroll
        for (int k = 0; k < D; ++k) { wt[k] = b2f(Wt[k * D + lane]); wp[k] = b2f(Wp[k * D + lane]); }
        bsum = b2f(((const unsigned short*)btv)[lane]) + b2f(((const unsigned short*)bpv)[lane]);
    }

    const int nW = gridDim.x << 2;
    for (int r = (blockIdx.x << 2) + wid; r < N_NODES; r += nW) {
        float x = fp32mode ? ((const float*)featv)[r * D + lane]
                           : b2f(((const unsigned short*)featv)[r * D + lane]);
        float at = 0.f, ap = 0.f;
#pragma unroll
        for (int k = 0; k < D; ++k) {
            float f = __shfl(x, k, 64);
            at = fmaf(f, wt[k], at);
            ap = fmaf(f, wp[k], ap);
        }
        float res = at + ap + bsum - ord2f(M[r * D + lane]);
        if (fp32mode) ((float*)outv)[r * D + lane] = res;
        else          ((unsigned short*)outv)[r * D + lane] = f2b(res);
    }
}

extern "C" void kernel_launch(void* const* d_in, const int* in_sizes, int n_in,
                              void* d_out, int out_size, void* d_ws, size_t ws_size,
                              hipStream_t stream) {
    unsigned* flags = (unsigned*)d_ws;   // [0..63] flags/pad, M at +256 (12.8 MB)

    detect_mode<<<1, 128, 0, stream>>>(d_in[0], d_in[1], flags);
    node_theta<<<1024, 256, 0, stream>>>(d_in[0], d_in[3], flags, d_out);
    edge_scatter<<<N_EDGES / 4, 256, 0, stream>>>(d_in[1], d_in[2], d_out, flags);
    finalize<<<1024, 256, 0, stream>>>(d_in[0], d_in[3], d_in[4], d_in[5], d_in[6],
                                       flags, d_out);
}